// Round 2
// baseline (36.191 us; speedup 1.0000x reference)
//
#include <hip/hip_runtime.h>
#include <hip/hip_bf16.h>
#include <cstdint>
#include <cstddef>

// out[b,c] = bias[c] + sum_i x[b,i]*(W1[i,c] + sum_j W2[i,j,c]*x[b,j])
// W flat layout: W1[i,c] = W[i*10+c]; W2[i,j,c] = W[7840 + i*7840 + j*10 + c]

typedef short short8 __attribute__((ext_vector_type(8)));
typedef float f32x4 __attribute__((ext_vector_type(4)));

#define NB   128    // batch
#define DD   784    // feature dim
#define NC   10     // classes
#define KCH  112    // j-chunk per block (7*112 = 784 exact)
#define NKC  7
#define IG   16     // i per block
#define NG   49     // 49*16 = 784
#define NBLK (NG*NKC)   // 343
#define ROWS 160        // LDS rows: c*16 + il  (10 c x 16 i)
#define LDK  136        // LDS row stride in bf16 elems (128 + 8 pad)
#define PSTRIDE 352     // padded partial stride (>= 343)

__device__ __forceinline__ unsigned short f2bf(float f) {
  // round-to-nearest-even f32 -> bf16 (inputs are finite Gaussians, no NaN path)
  uint32_t u = __builtin_bit_cast(uint32_t, f);
  u += 0x7FFFu + ((u >> 16) & 1u);
  return (unsigned short)(u >> 16);
}

template <int ATOMIC>
__global__ __launch_bounds__(256, 2)
void bilinear_main(const float* __restrict__ x, const float* __restrict__ W,
                   const float* __restrict__ bias, float* __restrict__ P,
                   float* __restrict__ out) {
  __shared__ unsigned short ldsW[ROWS * LDK];  // 43,520 B

  const int tid  = threadIdx.x;
  const int blk  = blockIdx.x;
  const int g    = blk / NKC;
  const int kc   = blk - g * NKC;
  const int i0   = g * IG;
  const int lane = tid & 63;
  const int w    = tid >> 6;      // wave 0..3
  const int h    = w & 1;         // batch half
  const int wm   = w >> 1;        // c half (tiles 5*wm .. 5*wm+4)
  const int l15  = lane & 15;
  const int q    = lane >> 4;     // lane quad
  const int jbase = kc * KCH;

  // ---- B operand: x-hat fragments in registers (reused across all i) ----
  // B[k][n]: lane holds x_bf16[b = h*64+bg*16+l15][j = jbase + ks*32 + q*8 + e]
  short8 bq[4][4];
  #pragma unroll
  for (int bg = 0; bg < 4; ++bg) {
    const int b = h * 64 + bg * 16 + l15;
    const float* xrow = x + (size_t)b * DD + jbase;
    #pragma unroll
    for (int ks = 0; ks < 4; ++ks) {
      const int jloc = ks * 32 + q * 8;
      float v[8];
      if (jloc < KCH) {
        const float4 p0 = *(const float4*)(xrow + jloc);
        const float4 p1 = *(const float4*)(xrow + jloc + 4);
        v[0] = p0.x; v[1] = p0.y; v[2] = p0.z; v[3] = p0.w;
        v[4] = p1.x; v[5] = p1.y; v[6] = p1.z; v[7] = p1.w;
      } else {
        #pragma unroll
        for (int e = 0; e < 8; ++e) v[e] = 0.f;
      }
      short8 s;
      #pragma unroll
      for (int e = 0; e < 8; ++e) s[e] = (short)f2bf(v[e]);
      bq[bg][ks] = s;
    }
  }

  // ---- hoisted epilogue weights: x[b, i] in f32 (i = i0 + q*4 + r) ----
  float xv[4][4];  // [bg][r]
  #pragma unroll
  for (int bg = 0; bg < 4; ++bg) {
    const int b = h * 64 + bg * 16 + l15;
    #pragma unroll
    for (int r = 0; r < 4; ++r)
      xv[bg][r] = x[(size_t)b * DD + i0 + q * 4 + r];
  }

  // ---- stage W2 chunk -> LDS, transposed to rows (c*16+il), bf16, b64 writes ----
  // thread quad f = il*320 + c*32 + jq ; element (i0+il, j = jbase+4*jq+e, c)
  for (int it = 0; it < 20; ++it) {
    const int f  = it * 256 + tid;      // 0..5119
    const int jq = f & 31;
    const int c  = (f >> 5) % NC;
    const int il = f / 320;
    const int jj = jq * 4;
    ushort4 sv = make_ushort4(0, 0, 0, 0);
    if (jj < KCH) {
      const float* p = W + 7840 + (size_t)(i0 + il) * 7840 + (size_t)(jbase + jj) * NC + c;
      sv.x = f2bf(p[0]);
      sv.y = f2bf(p[10]);
      sv.z = f2bf(p[20]);
      sv.w = f2bf(p[30]);
    }
    *(ushort4*)&ldsW[(c * 16 + il) * LDK + jj] = sv;
  }
  __syncthreads();

  // ---- MFMA: A = W2-tile (m-rows: c fixed per tile, i = i0 + m), B = x-hat ----
  float yacc[4][5] = {};   // [bg][t]  (c = wm*5 + t is static per slot)
  const int tbase = wm * 5;
  #pragma unroll
  for (int t = 0; t < 5; ++t) {
    const int tile = tbase + t;          // tile index == c
    f32x4 acc[4] = {};
    const unsigned short* arow = &ldsW[(tile * 16 + l15) * LDK + q * 8];
    #pragma unroll
    for (int ks = 0; ks < 4; ++ks) {
      const short8 a = *(const short8*)(arow + ks * 32);
      #pragma unroll
      for (int bg = 0; bg < 4; ++bg)
        acc[bg] = __builtin_amdgcn_mfma_f32_16x16x32_bf16(a, bq[bg][ks], acc[bg], 0, 0, 0);
    }
    // epilogue: y[b,c] += x[b,i] * (T[b,i,c] + W1[i,c] once at kc==0)
    #pragma unroll
    for (int r = 0; r < 4; ++r) {
      float w1 = 0.f;
      if (kc == 0) w1 = W[(i0 + q * 4 + r) * NC + tile];
      #pragma unroll
      for (int bg = 0; bg < 4; ++bg)
        yacc[bg][t] += xv[bg][r] * (acc[bg][r] + w1);
    }
  }

  // ---- reduce over lane-quads (each q holds a different i-subset), then emit ----
  #pragma unroll
  for (int bg = 0; bg < 4; ++bg) {
    #pragma unroll
    for (int t = 0; t < 5; ++t) {
      float v = yacc[bg][t];
      v += __shfl_down(v, 16);   // q -> q+1
      v += __shfl_down(v, 32);   // (q,q+1) -> (q+2,q+3)
      if (q == 0) {
        const int bc = (h * 64 + bg * 16 + l15) * NC + tbase + t;
        if constexpr (ATOMIC == 0) {
          P[(size_t)bc * PSTRIDE + blk] = v;
        } else {
          if (blk == 0) v += bias[tbase + t];
          atomicAdd(&out[bc], v);
        }
      }
    }
  }
}

__global__ __launch_bounds__(64)
void reduce_partials(const float* __restrict__ P, const float* __restrict__ bias,
                     float* __restrict__ out) {
  const int bc = blockIdx.x;   // 0..1279
  const int l  = threadIdx.x;  // 0..63
  float s = 0.f;
  for (int k = l; k < NBLK; k += 64) s += P[(size_t)bc * PSTRIDE + k];
  #pragma unroll
  for (int off = 32; off; off >>= 1) s += __shfl_down(s, off);
  if (l == 0) out[bc] = s + bias[bc % NC];
}

extern "C" void kernel_launch(void* const* d_in, const int* in_sizes, int n_in,
                              void* d_out, int out_size, void* d_ws, size_t ws_size,
                              hipStream_t stream) {
  const float* x    = (const float*)d_in[0];
  const float* W    = (const float*)d_in[1];
  const float* bias = (const float*)d_in[2];
  float* out = (float*)d_out;
  float* P   = (float*)d_ws;

  const size_t need = (size_t)NB * NC * PSTRIDE * sizeof(float);  // ~1.8 MB
  if (ws_size >= need) {
    bilinear_main<0><<<NBLK, 256, 0, stream>>>(x, W, bias, P, out);
    reduce_partials<<<NB * NC, 64, 0, stream>>>(P, bias, out);
  } else {
    hipMemsetAsync(d_out, 0, (size_t)NB * NC * sizeof(float), stream);
    bilinear_main<1><<<NBLK, 256, 0, stream>>>(x, W, bias, P, out);
  }
}

// Round 3
// 22.500 us; speedup vs baseline: 1.6085x; 1.6085x over previous
//
#include <hip/hip_runtime.h>
#include <hip/hip_bf16.h>
#include <cstdint>
#include <cstddef>

// out[b,c] = bias[c] + sum_i x[b,i]*(W1[i,c] + sum_j W2[i,j,c]*x[b,j])
// W flat layout: W1[i,c] = W[i*10+c]; W2[i,j,c] = W[7840 + i*7840 + j*10 + c]

typedef short short8 __attribute__((ext_vector_type(8)));
typedef float f32x4 __attribute__((ext_vector_type(4)));

#define NB   128
#define DD   784
#define NC   10
#define KCH  112    // j-chunk per block (7*112 = 784)
#define NKC  7
#define IG   16     // i per block
#define NG   49
#define NBLK (NG*NKC)   // 343
#define LDK  136        // LDS row stride in bf16 elems (128 + 8 pad)
#define LDKU 68         // same, in u32
#define PSTRIDE 352     // padded partial stride (>= 343)

__device__ __forceinline__ uint32_t f2bfbits(float f) {
  // round-to-nearest-even f32 -> bf16 (finite inputs)
  uint32_t u = __builtin_bit_cast(uint32_t, f);
  u += 0x7FFFu + ((u >> 16) & 1u);
  return u >> 16;
}

template <int ATOMIC>
__global__ __launch_bounds__(512, 4)
void bilinear_main(const float* __restrict__ x, const float* __restrict__ W,
                   const float* __restrict__ bias, float* __restrict__ P,
                   float* __restrict__ out) {
  __shared__ unsigned short ldsW[160 * LDK];  // 43,520 B
  uint32_t* lds32 = (uint32_t*)ldsW;

  const int tid  = threadIdx.x;
  const int blk  = blockIdx.x;
  const int g    = blk / NKC;
  const int kc   = blk - g * NKC;
  const int i0   = g * IG;
  const int lane = tid & 63;
  const int w    = tid >> 6;      // wave 0..7
  const int wm   = w >> 2;        // c half (tiles 5*wm .. 5*wm+4)
  const int bq2  = w & 3;         // batch quarter (32 batches)
  const int l15  = lane & 15;
  const int q    = lane >> 4;     // lane quad
  const int jbase = kc * KCH;

  // ---- stage W2 chunk -> LDS bf16 transposed; COALESCED float4 loads ----
  // group gi = il*56 + k covers i=i0+il, j = jbase+2k..2k+1, c=0..9 (20 floats,
  // 16B-aligned, contiguous). Pack (j,j+1) per c into one ds_write_b32.
  {
    const float* w2base = W + 7840 + (size_t)i0 * 7840 + (size_t)jbase * NC;
    #pragma unroll
    for (int half = 0; half < 2; ++half) {
      const int gi = half * 512 + tid;     // 0..895 used
      if (gi < 896) {
        const int il = gi / 56;
        const int k  = gi - il * 56;
        const float* p = w2base + il * 7840 + k * 20;
        const float4 a0 = ((const float4*)p)[0];
        const float4 a1 = ((const float4*)p)[1];
        const float4 a2 = ((const float4*)p)[2];
        const float4 a3 = ((const float4*)p)[3];
        const float4 a4 = ((const float4*)p)[4];
        const float v[20] = {a0.x,a0.y,a0.z,a0.w, a1.x,a1.y,a1.z,a1.w,
                             a2.x,a2.y,a2.z,a2.w, a3.x,a3.y,a3.z,a3.w,
                             a4.x,a4.y,a4.z,a4.w};
        #pragma unroll
        for (int c = 0; c < 10; ++c) {
          const uint32_t lo = f2bfbits(v[c]);
          const uint32_t hi = f2bfbits(v[c + 10]);
          lds32[(c * 16 + il) * LDKU + k] = lo | (hi << 16);
        }
      }
    }
    // zero the k-pad columns j' in [112,128) for all 160 rows (avoid NaN*0)
    for (int idx = tid; idx < 160 * 8; idx += 512) {
      const int row  = idx >> 3;
      const int colu = idx & 7;
      lds32[row * LDKU + 56 + colu] = 0;
    }
  }

  // ---- B operand: x-hat fragments in registers (reused across all i) ----
  // lane holds x_bf16[b = bq2*32+bg*16+l15][j = jbase + ks*32 + q*8 + e]
  short8 bq[2][4];
  #pragma unroll
  for (int bg = 0; bg < 2; ++bg) {
    const int b = bq2 * 32 + bg * 16 + l15;
    const float* xrow = x + (size_t)b * DD + jbase;
    #pragma unroll
    for (int ks = 0; ks < 4; ++ks) {
      const int jloc = ks * 32 + q * 8;
      float v[8];
      if (jloc < KCH) {
        const float4 p0 = *(const float4*)(xrow + jloc);
        const float4 p1 = *(const float4*)(xrow + jloc + 4);
        v[0] = p0.x; v[1] = p0.y; v[2] = p0.z; v[3] = p0.w;
        v[4] = p1.x; v[5] = p1.y; v[6] = p1.z; v[7] = p1.w;
      } else {
        #pragma unroll
        for (int e = 0; e < 8; ++e) v[e] = 0.f;
      }
      short8 s;
      #pragma unroll
      for (int e = 0; e < 8; ++e) s[e] = (short)f2bfbits(v[e]);
      bq[bg][ks] = s;
    }
  }

  // ---- hoisted epilogue weights: x[b, i] in f32 (i = i0 + q*4 + r) ----
  float xv[2][4];
  #pragma unroll
  for (int bg = 0; bg < 2; ++bg) {
    const int b = bq2 * 32 + bg * 16 + l15;
    #pragma unroll
    for (int r = 0; r < 4; ++r)
      xv[bg][r] = x[(size_t)b * DD + i0 + q * 4 + r];
  }

  __syncthreads();

  // ---- MFMA: A = W2-tile (rows: c fixed per tile, m = i-local), B = x-hat ----
  float yacc[2][5] = {};   // [bg][t]  (c = wm*5 + t static per slot)
  const int tbase = wm * 5;
  #pragma unroll
  for (int t = 0; t < 5; ++t) {
    const int tile = tbase + t;          // tile index == c
    f32x4 acc[2] = {};
    const unsigned short* arow = &ldsW[(tile * 16 + l15) * LDK + q * 8];
    #pragma unroll
    for (int ks = 0; ks < 4; ++ks) {
      const short8 a = *(const short8*)(arow + ks * 32);
      #pragma unroll
      for (int bg = 0; bg < 2; ++bg)
        acc[bg] = __builtin_amdgcn_mfma_f32_16x16x32_bf16(a, bq[bg][ks], acc[bg], 0, 0, 0);
    }
    // epilogue: y[b,c] += x[b,i] * (T[b,i,c] + W1[i,c] once at kc==0)
    #pragma unroll
    for (int r = 0; r < 4; ++r) {
      float w1 = 0.f;
      if (kc == 0) w1 = W[(i0 + q * 4 + r) * NC + tile];
      #pragma unroll
      for (int bg = 0; bg < 2; ++bg)
        yacc[bg][t] += xv[bg][r] * (acc[bg][r] + w1);
    }
  }

  // ---- reduce over lane-quads (each q holds a different i-subset), emit ----
  #pragma unroll
  for (int bg = 0; bg < 2; ++bg) {
    #pragma unroll
    for (int t = 0; t < 5; ++t) {
      float v = yacc[bg][t];
      v += __shfl_down(v, 16);
      v += __shfl_down(v, 32);
      if (q == 0) {
        const int bc = (bq2 * 32 + bg * 16 + l15) * NC + tbase + t;
        if constexpr (ATOMIC == 0) {
          P[(size_t)bc * PSTRIDE + blk] = v;
        } else {
          if (blk == 0) v += bias[tbase + t];
          atomicAdd(&out[bc], v);
        }
      }
    }
  }
}

__global__ __launch_bounds__(64)
void reduce_partials(const float* __restrict__ P, const float* __restrict__ bias,
                     float* __restrict__ out) {
  const int bc = blockIdx.x;   // 0..1279
  const int l  = threadIdx.x;  // 0..63
  float s = 0.f;
  for (int k = l; k < NBLK; k += 64) s += P[(size_t)bc * PSTRIDE + k];
  #pragma unroll
  for (int off = 32; off; off >>= 1) s += __shfl_down(s, off);
  if (l == 0) out[bc] = s + bias[bc % NC];
}

extern "C" void kernel_launch(void* const* d_in, const int* in_sizes, int n_in,
                              void* d_out, int out_size, void* d_ws, size_t ws_size,
                              hipStream_t stream) {
  const float* x    = (const float*)d_in[0];
  const float* W    = (const float*)d_in[1];
  const float* bias = (const float*)d_in[2];
  float* out = (float*)d_out;
  float* P   = (float*)d_ws;

  const size_t need = (size_t)NB * NC * PSTRIDE * sizeof(float);  // ~1.8 MB
  if (ws_size >= need) {
    bilinear_main<0><<<NBLK, 512, 0, stream>>>(x, W, bias, P, out);
    reduce_partials<<<NB * NC, 64, 0, stream>>>(P, bias, out);
  } else {
    hipMemsetAsync(d_out, 0, (size_t)NB * NC * sizeof(float), stream);
    bilinear_main<1><<<NBLK, 512, 0, stream>>>(x, W, bias, P, out);
  }
}